// Round 6
// baseline (1854.914 us; speedup 1.0000x reference)
//
#include <hip/hip_runtime.h>

typedef unsigned short u16;
typedef unsigned int u32;
typedef __attribute__((ext_vector_type(8))) short short8;
typedef __attribute__((ext_vector_type(4))) float floatx4;

#define LN_EPS 1e-5f
#define REG 6291456L   // 16*512*768 elems: Q|K|V region stride in qkvg

__device__ __forceinline__ float b2f(u16 u) {
    return __builtin_bit_cast(float, (u32)u << 16);
}
__device__ __forceinline__ u16 f2b(float f) {
    u32 x = __builtin_bit_cast(u32, f);
    return (u16)((x + 0x7fffu + ((x >> 16) & 1u)) >> 16);
}

// async global->LDS, 16B per lane; LDS dest must be base + lane*16 (m97/m104)
__device__ __forceinline__ void gload16(const u16* g, u16* l) {
    __builtin_amdgcn_global_load_lds(
        (const __attribute__((address_space(1))) void*)g,
        (__attribute__((address_space(3))) void*)l, 16, 0, 0);
}

// ---------------------------------------------------------------------------
// Unified MFMA GEMM with global_load_lds staging (unpadded LDS, stride 32).
// C = A[M,K] @ BT[Nb,K]^T (+bias), A/BT bf16. Block 256 = 4 waves (2x2).
// BN_=192: wave 64x96 (4x6 mfma 16x16x32). M-tile 128. SMAJ=1: block rows =
// 64 s x 2 i (m = s*2 + i_local, iL0 = by*2) -> dense scatter writes.
// Epilogues:
//  0 TOK   : C[(by*128+ml)*Nb + n] bf16                       [FFN, ld=Nb]
//  3 VT    : C[h*393216 + (s*12+d)*512 + iL]  (s-blocked)     [row V^T]
//  8 QKROW : t=n/192 -> C+t*REG, head-major (s-major tiling)  [row Q,K]
//  9 COLQKV: t=n/192 -> C+t*REG, token layout (s-major)       [col q,k,v]
// bias idx: EPI 8/9: t*768+colbase+(n%192); else colbase+n.
// ---------------------------------------------------------------------------
template<int BN_, int EPI, int RELU, int HASBIAS, int SMAJ>
__global__ __launch_bounds__(256, 2) void gemm_dma(
    const u16* __restrict__ A, const u16* __restrict__ BT,
    const float* __restrict__ bias, void* __restrict__ C,
    int Nb, int K, long sA, long sB, long sC, int colbase)
{
    constexpr int NCH = (128 + BN_) / 64;   // 16B DMA chunks per thread
    constexpr int JF  = BN_ / 32;           // B frags per wave
    __shared__ u16 lds[(128 + BN_) * 32];   // A[128][32] then B[BN_][32]

    const u16* Az = A + (long)blockIdx.z * sA;
    const u16* Bz = BT + (long)blockIdx.z * sB;
    const int n0 = blockIdx.x * BN_;
    const int tid = threadIdx.x;
    const int lane = tid & 63;
    const int wm = ((tid >> 6) >> 1) * 64;
    const int wn = ((tid >> 6) & 1) * (BN_ / 2);
    const int lrow = lane & 15;
    const int quad = lane >> 4;

    floatx4 acc[4][JF];
#pragma unroll
    for (int i = 0; i < 4; i++)
#pragma unroll
        for (int j = 0; j < JF; j++)
            acc[i][j] = (floatx4){0.f, 0.f, 0.f, 0.f};

    for (int kt = 0; kt < K; kt += 32) {
#pragma unroll
        for (int it = 0; it < NCH; it++) {
            const int idx = tid + it * 256;
            const u16* src;
            if (idx < 512) {                 // A chunks (wave-uniform branch)
                const int row = idx >> 2;
                const int ch  = (idx & 3) * 8;
                const long grow = SMAJ
                    ? ((long)(row >> 1) * 512 + (blockIdx.y << 1) + (row & 1))
                    : ((long)blockIdx.y * 128 + row);
                src = Az + grow * K + kt + ch;
            } else {                         // B chunks
                const int bidx = idx - 512;
                const int row = bidx >> 2;
                const int ch  = (bidx & 3) * 8;
                src = Bz + (long)(n0 + row) * K + kt + ch;
            }
            gload16(src, &lds[idx * 8]);
        }
        __syncthreads();

        short8 af[4], bfr[JF];
#pragma unroll
        for (int i = 0; i < 4; i++)
            af[i] = *(const short8*)&lds[(wm + i * 16 + lrow) * 32 + quad * 8];
#pragma unroll
        for (int j = 0; j < JF; j++)
            bfr[j] = *(const short8*)&lds[4096 + (wn + j * 16 + lrow) * 32 + quad * 8];
#pragma unroll
        for (int i = 0; i < 4; i++)
#pragma unroll
            for (int j = 0; j < JF; j++)
                acc[i][j] = __builtin_amdgcn_mfma_f32_16x16x32_bf16(
                    af[i], bfr[j], acc[i][j], 0, 0, 0);
        __syncthreads();
    }

    // D element: row = quad*4+r, col = lane&15 (verified m89/m91)
#pragma unroll
    for (int j = 0; j < JF; j++) {
        const int n = n0 + wn + j * 16 + lrow;
        int t = 0, jj = n;
        if (EPI == 8 || EPI == 9) { t = n / 192; jj = n - t * 192; }
        const int hl = jj / 12;
        const int cc = jj - hl * 12;
        float bv = 0.f;
        if (HASBIAS)
            bv = (EPI == 8 || EPI == 9) ? bias[t * 768 + colbase + jj]
                                        : bias[colbase + n];
#pragma unroll
        for (int i = 0; i < 4; i++) {
            const int mb = wm + i * 16 + quad * 4;
#pragma unroll
            for (int r = 0; r < 4; r++) {
                const int ml = mb + r;
                float v = acc[i][j][r] + bv;
                if (RELU) v = fmaxf(v, 0.f);
                if (EPI == 0) {
                    const long m = (long)blockIdx.y * 128 + ml;
                    ((u16*)C)[m * Nb + n] = f2b(v);
                } else if (EPI == 3) {
                    const int gm = blockIdx.y * 128 + ml;
                    const int s = gm >> 9, iL = gm & 511;
                    ((u16*)C)[(long)hl * 393216 + (long)(s * 12 + cc) * 512 + iL] = f2b(v);
                } else if (EPI == 8) {
                    const int s = ml >> 1, iL = (blockIdx.y << 1) + (ml & 1);
                    ((u16*)C)[(long)t * REG + ((long)hl * 512 + iL) * 768 + s * 12 + cc] = f2b(v);
                } else if (EPI == 9) {
                    const int s = ml >> 1, l = (blockIdx.y << 1) + (ml & 1);
                    ((u16*)C)[(long)t * REG + (long)hl * 393216 + (long)l * 768 + s * 12 + cc] = f2b(v);
                }
            }
        }
    }
}

// ---------------------------------------------------------------------------
// Flash row attention for one 16-head group: per block one (head, 32-row
// Q-tile). S = Q@K^T (512 cols, exact softmax, no scaling), P@V.
// Qg/Kg: [h][i][768]; Vt: [h][s*12+d][i]; Out: rowout scatter (EPI-4 mapping).
// 4 waves: phase1 wave = (row-half wr, col-half wc); phase4 wave = 192-col slice.
// ---------------------------------------------------------------------------
__global__ __launch_bounds__(256, 2) void flash_row_kernel(
    const u16* __restrict__ Qg, const u16* __restrict__ Kg,
    const u16* __restrict__ Vt, u16* __restrict__ Out, int hbase)
{
    __shared__ __align__(16) u16 lds[17408]; // ph1: Q32x32 @0, K512x32 @1024; ph3: P 32x520 @0
    __shared__ float pmx[2][32];
    __shared__ float psm[2][32];

    const int h  = blockIdx.y;
    const int i0 = blockIdx.x * 32;
    const u16* Qh = Qg + (long)h * 393216;
    const u16* Kh = Kg + (long)h * 393216;
    const u16* Vh = Vt + (long)h * 393216;
    const int tid  = threadIdx.x;
    const int w    = tid >> 6;
    const int wr   = w >> 1;
    const int wc   = w & 1;
    const int lane = tid & 63;
    const int lrow = lane & 15;
    const int quad = lane >> 4;

    floatx4 acc[16];
#pragma unroll
    for (int j = 0; j < 16; j++) acc[j] = (floatx4){0.f, 0.f, 0.f, 0.f};

    for (int kt = 0; kt < 768; kt += 32) {
        // stage Q-tile (32x32 @0) + K panel (512x32 @1024): 2176 chunks
        if (tid < 128) {
            const int row = tid >> 2, ch = (tid & 3) * 8;
            gload16(Qh + (long)(i0 + row) * 768 + kt + ch, &lds[tid * 8]);
        } else {
            const int b = tid - 128;
            const int row = b >> 2, ch = (b & 3) * 8;
            gload16(Kh + (long)row * 768 + kt + ch, &lds[tid * 8]);
        }
#pragma unroll
        for (int it = 1; it < 8; it++) {
            const int idx = tid + it * 256;
            const int b = idx - 128;
            const int row = b >> 2, ch = (b & 3) * 8;
            gload16(Kh + (long)row * 768 + kt + ch, &lds[idx * 8]);
        }
        if (tid < 128) {
            const int idx = tid + 2048;
            const int b = idx - 128;
            const int row = b >> 2, ch = (b & 3) * 8;
            gload16(Kh + (long)row * 768 + kt + ch, &lds[idx * 8]);
        }
        __syncthreads();
        const short8 af = *(const short8*)&lds[(wr * 16 + lrow) * 32 + quad * 8];
#pragma unroll
        for (int j = 0; j < 16; j++) {
            const short8 bf = *(const short8*)
                &lds[1024 + (wc * 256 + j * 16 + lrow) * 32 + quad * 8];
            acc[j] = __builtin_amdgcn_mfma_f32_16x16x32_bf16(af, bf, acc[j], 0, 0, 0);
        }
        __syncthreads();
    }

    // ---- exact softmax over 512 cols (rows: row32 + r) ----
    const int row32 = wr * 16 + quad * 4;
    float pm[4], inv[4];
#pragma unroll
    for (int r = 0; r < 4; r++) {
        float m = -3.0e38f;
#pragma unroll
        for (int j = 0; j < 16; j++) m = fmaxf(m, acc[j][r]);
#pragma unroll
        for (int d = 1; d < 16; d <<= 1) m = fmaxf(m, __shfl_xor(m, d));
        pm[r] = m;
        if (lrow == 0) pmx[wc][row32 + r] = m;
    }
    __syncthreads();
#pragma unroll
    for (int r = 0; r < 4; r++) {
        const float m = fmaxf(pm[r], pmx[1 ^ wc][row32 + r]);
        float s = 0.f;
#pragma unroll
        for (int j = 0; j < 16; j++) {
            const float e = __expf(acc[j][r] - m);
            acc[j][r] = e; s += e;
        }
#pragma unroll
        for (int d = 1; d < 16; d <<= 1) s += __shfl_xor(s, d);
        if (lrow == 0) psm[wc][row32 + r] = s;
    }
    __syncthreads();
#pragma unroll
    for (int r = 0; r < 4; r++)
        inv[r] = 1.0f / (psm[0][row32 + r] + psm[1][row32 + r]);

    // ---- P (bf16, normalized) -> LDS, stride 520 (stage region dead) ----
#pragma unroll
    for (int j = 0; j < 16; j++)
#pragma unroll
        for (int r = 0; r < 4; r++)
            lds[(row32 + r) * 520 + wc * 256 + j * 16 + lrow] =
                f2b(acc[j][r] * inv[r]);
    __syncthreads();

    // ---- PV: out[32x768] = P @ V ; V^T frags straight from global ----
    floatx4 acc2[2][12];
#pragma unroll
    for (int i = 0; i < 2; i++)
#pragma unroll
        for (int j = 0; j < 12; j++) acc2[i][j] = (floatx4){0.f, 0.f, 0.f, 0.f};

    for (int kt2 = 0; kt2 < 512; kt2 += 32) {
        short8 af2[2];
#pragma unroll
        for (int i = 0; i < 2; i++)
            af2[i] = *(const short8*)&lds[(i * 16 + lrow) * 520 + kt2 + quad * 8];
#pragma unroll
        for (int j = 0; j < 12; j++) {
            const int n = w * 192 + j * 16 + lrow;
            const short8 bf = *(const short8*)(Vh + (long)n * 512 + kt2 + quad * 8);
#pragma unroll
            for (int i = 0; i < 2; i++)
                acc2[i][j] = __builtin_amdgcn_mfma_f32_16x16x32_bf16(
                    af2[i], bf, acc2[i][j], 0, 0, 0);
        }
    }

    // ---- scatter (verified EPI-4 mapping) ----
#pragma unroll
    for (int j = 0; j < 12; j++) {
        const int n = w * 192 + j * 16 + lrow;
        const int s = n / 12, d = n - (n / 12) * 12;
#pragma unroll
        for (int i = 0; i < 2; i++)
#pragma unroll
            for (int r = 0; r < 4; r++) {
                const int m = i * 16 + quad * 4 + r;
                Out[((long)s * 512 + i0 + m) * 768 + hbase + h * 12 + d] =
                    f2b(acc2[i][j][r]);
            }
    }
}

// ---------------------------------------------------------------------------
// x (f32) -> xb (bf16), 8 elems/thread
// ---------------------------------------------------------------------------
__global__ __launch_bounds__(256) void cast_kernel(
    const float* __restrict__ X, u16* __restrict__ Xb)
{
    const long i = ((long)blockIdx.x * 256 + threadIdx.x) * 8;
    float4 a = *(const float4*)(X + i);
    float4 b = *(const float4*)(X + i + 4);
    u16 t8[8] = { f2b(a.x), f2b(a.y), f2b(a.z), f2b(a.w),
                  f2b(b.x), f2b(b.y), f2b(b.z), f2b(b.w) };
    *(uint4*)(Xb + i) = *(const uint4*)t8;
}

// ---------------------------------------------------------------------------
// 32x32 tiled transpose + cast: Out[c][r] = bf16(In[r][c]); Out ld = R
// ---------------------------------------------------------------------------
__global__ __launch_bounds__(256) void transpose_kernel(
    const float* __restrict__ In, u16* __restrict__ Out, int R, int Ccols)
{
    __shared__ u16 tile[32][33];
    int tx = threadIdx.x & 31;
    int ty = threadIdx.x >> 5;
    int c0 = blockIdx.x * 32;
    int r0 = blockIdx.y * 32;
#pragma unroll
    for (int rr = 0; rr < 32; rr += 8)
        tile[ty + rr][tx] = f2b(In[(long)(r0 + ty + rr) * Ccols + c0 + tx]);
    __syncthreads();
#pragma unroll
    for (int rr = 0; rr < 32; rr += 8)
        Out[(long)(c0 + ty + rr) * R + r0 + tx] = tile[tx][ty + rr];
}

// W[768][2304] -> wPqk[1536][768]: row p: hg=p/384, t=(p%384)/192, j=p%192
__global__ __launch_bounds__(256) void pack_qk_kernel(
    const float* __restrict__ In, u16* __restrict__ Out)
{
    __shared__ u16 tile[32][33];
    int tx = threadIdx.x & 31;
    int ty = threadIdx.x >> 5;
    int p0 = blockIdx.x * 32;
    int k0 = blockIdx.y * 32;
    int hg = p0 / 384, rem = p0 % 384;
    int t = rem / 192, j0 = rem % 192;
    int c0 = t * 768 + hg * 192 + j0;
#pragma unroll
    for (int rr = 0; rr < 32; rr += 8)
        tile[ty + rr][tx] = f2b(In[(long)(k0 + ty + rr) * 2304 + c0 + tx]);
    __syncthreads();
#pragma unroll
    for (int rr = 0; rr < 32; rr += 8)
        Out[(long)(p0 + ty + rr) * 768 + k0 + tx] = tile[tx][ty + rr];
}

// W[768][2304] -> wPv[768][768]: row p: hg=p/192, j=p%192 -> col 1536+hg*192+j
__global__ __launch_bounds__(256) void pack_v_kernel(
    const float* __restrict__ In, u16* __restrict__ Out)
{
    __shared__ u16 tile[32][33];
    int tx = threadIdx.x & 31;
    int ty = threadIdx.x >> 5;
    int p0 = blockIdx.x * 32;
    int k0 = blockIdx.y * 32;
    int hg = p0 / 192, j0 = p0 % 192;
    int c0 = 1536 + hg * 192 + j0;
#pragma unroll
    for (int rr = 0; rr < 32; rr += 8)
        tile[ty + rr][tx] = f2b(In[(long)(k0 + ty + rr) * 2304 + c0 + tx]);
    __syncthreads();
#pragma unroll
    for (int rr = 0; rr < 32; rr += 8)
        Out[(long)(p0 + ty + rr) * 768 + k0 + tx] = tile[tx][ty + rr];
}

// W[768][2304] -> wPcol[2304][768]: row p: hg=p/576, t=(p%576)/192, j=p%192
__global__ __launch_bounds__(256) void qkv_pack_kernel(
    const float* __restrict__ In, u16* __restrict__ Out)
{
    __shared__ u16 tile[32][33];
    int tx = threadIdx.x & 31;
    int ty = threadIdx.x >> 5;
    int p0 = blockIdx.x * 32;
    int k0 = blockIdx.y * 32;
    int hg = p0 / 576, r0 = p0 % 576;
    int t = r0 / 192, j0 = r0 % 192;
    int c0 = t * 768 + hg * 192 + j0;
#pragma unroll
    for (int rr = 0; rr < 32; rr += 8)
        tile[ty + rr][tx] = f2b(In[(long)(k0 + ty + rr) * 2304 + c0 + tx]);
    __syncthreads();
#pragma unroll
    for (int rr = 0; rr < 32; rr += 8)
        Out[(long)(p0 + ty + rr) * 768 + k0 + tx] = tile[tx][ty + rr];
}

// ---------------------------------------------------------------------------
// out = LN(Xa + Xb) * g + be ; Xa dtype AF (1=f32), Xb dtype BF, out OF
// ---------------------------------------------------------------------------
template<int AF, int BF, int OF>
__global__ __launch_bounds__(256) void ln_add_kernel(
    const void* __restrict__ Xa, const void* __restrict__ Xb,
    const float* __restrict__ g, const float* __restrict__ be,
    void* __restrict__ Out)
{
    const long r = blockIdx.x;
    int t = threadIdx.x;
    float v[3]; float sm = 0.f, s2 = 0.f;
#pragma unroll
    for (int e = 0; e < 3; e++) {
        long c = r * 768 + t + e * 256;
        float xa = AF ? ((const float*)Xa)[c] : b2f(((const u16*)Xa)[c]);
        float xb = BF ? ((const float*)Xb)[c] : b2f(((const u16*)Xb)[c]);
        float x = xa + xb;
        v[e] = x; sm += x; s2 += x * x;
    }
    __shared__ float r1[256], r2[256];
    r1[t] = sm; r2[t] = s2;
    __syncthreads();
    for (int o = 128; o > 0; o >>= 1) {
        if (t < o) { r1[t] += r1[t + o]; r2[t] += r2[t + o]; }
        __syncthreads();
    }
    float mean = r1[0] * (1.0f / 768.0f);
    float var  = r2[0] * (1.0f / 768.0f) - mean * mean;
    float rstd = rsqrtf(var + LN_EPS);
#pragma unroll
    for (int e = 0; e < 3; e++) {
        int c = t + e * 256;
        float o = (v[e] - mean) * rstd * g[c] + be[c];
        if (OF) ((float*)Out)[r * 768 + c] = o;
        else    ((u16*)Out)[r * 768 + c] = f2b(o);
    }
}

// ---------------------------------------------------------------------------
// Fused double-LN: y(f32) = LN2( X + LN1(A + B) ); also writes ybf (bf16)
// ---------------------------------------------------------------------------
__global__ __launch_bounds__(256) void ln_ln_kernel(
    const u16* __restrict__ A, const u16* __restrict__ B,
    const float* __restrict__ X,
    const float* __restrict__ g1, const float* __restrict__ be1,
    const float* __restrict__ g2, const float* __restrict__ be2,
    float* __restrict__ Out, u16* __restrict__ Outb)
{
    const long r = blockIdx.x;
    int t = threadIdx.x;
    __shared__ float r1[256], r2[256];

    float u[3]; float sm = 0.f, s2 = 0.f;
#pragma unroll
    for (int e = 0; e < 3; e++) {
        long c = r * 768 + t + e * 256;
        float x = b2f(A[c]) + b2f(B[c]);
        u[e] = x; sm += x; s2 += x * x;
    }
    r1[t] = sm; r2[t] = s2;
    __syncthreads();
    for (int o = 128; o > 0; o >>= 1) {
        if (t < o) { r1[t] += r1[t + o]; r2[t] += r2[t + o]; }
        __syncthreads();
    }
    float mean1 = r1[0] * (1.0f / 768.0f);
    float var1  = r2[0] * (1.0f / 768.0f) - mean1 * mean1;
    float rstd1 = rsqrtf(var1 + LN_EPS);
    __syncthreads();

    float w[3]; sm = 0.f; s2 = 0.f;
#pragma unroll
    for (int e = 0; e < 3; e++) {
        int c = t + e * 256;
        float tv = (u[e] - mean1) * rstd1 * g1[c] + be1[c];
        float wv = X[r * 768 + c] + tv;
        w[e] = wv; sm += wv; s2 += wv * wv;
    }
    r1[t] = sm; r2[t] = s2;
    __syncthreads();
    for (int o = 128; o > 0; o >>= 1) {
        if (t < o) { r1[t] += r1[t + o]; r2[t] += r2[t + o]; }
        __syncthreads();
    }
    float mean2 = r1[0] * (1.0f / 768.0f);
    float var2  = r2[0] * (1.0f / 768.0f) - mean2 * mean2;
    float rstd2 = rsqrtf(var2 + LN_EPS);
#pragma unroll
    for (int e = 0; e < 3; e++) {
        int c = t + e * 256;
        float o = (w[e] - mean2) * rstd2 * g2[c] + be2[c];
        Out[r * 768 + c] = o;
        Outb[r * 768 + c] = f2b(o);
    }
}

// ---------------------------------------------------------------------------
// Col attention for one 16-head group. Slices: [h'][l][s*12+c].
// Block = (h', l), 64 threads; thread i = query S-row.
// ---------------------------------------------------------------------------
__global__ __launch_bounds__(64) void col_attn_kernel(
    const u16* __restrict__ qc, const u16* __restrict__ kc,
    const u16* __restrict__ vc, u16* __restrict__ Out, int hbase)
{
    const int hh = blockIdx.x >> 9;
    const int l  = blockIdx.x & 511;
    const int i  = threadIdx.x;
    const long base = ((long)hh * 512 + l) * 768;
    __shared__ float Ks[64][12];
    __shared__ float Vs[64][12];
    float q[12];
#pragma unroll
    for (int c = 0; c < 12; c++) {
        q[c] = b2f(qc[base + i * 12 + c]);
        Ks[i][c] = b2f(kc[base + i * 12 + c]);
        Vs[i][c] = b2f(vc[base + i * 12 + c]);
    }
    __syncthreads();
    float sc[64];
#pragma unroll
    for (int j = 0; j < 64; j++) {
        float a = 0.f;
#pragma unroll
        for (int c = 0; c < 12; c++) a += q[c] * Ks[j][c];
        sc[j] = a;
    }
    float m = sc[0];
#pragma unroll
    for (int j = 1; j < 64; j++) m = fmaxf(m, sc[j]);
    float sum = 0.f;
#pragma unroll
    for (int j = 0; j < 64; j++) { sc[j] = __expf(sc[j] - m); sum += sc[j]; }
    float inv = 1.0f / sum;
    float o[12];
#pragma unroll
    for (int c = 0; c < 12; c++) o[c] = 0.f;
#pragma unroll
    for (int j = 0; j < 64; j++) {
        float p = sc[j] * inv;
#pragma unroll
        for (int c = 0; c < 12; c++) o[c] += p * Vs[j][c];
    }
    u16* op = Out + ((long)i * 512 + l) * 768 + hbase + hh * 12;
#pragma unroll
    for (int c = 0; c < 12; c++) op[c] = f2b(o[c]);
}

// ---------------------------------------------------------------------------
extern "C" void kernel_launch(void* const* d_in, const int* in_sizes, int n_in,
                              void* d_out, int out_size, void* d_ws, size_t ws_size,
                              hipStream_t stream)
{
    (void)in_sizes; (void)n_in; (void)out_size; (void)ws_size;

    const float* x     = (const float*)d_in[0];
    const float* w_row = (const float*)d_in[1];
    const float* b_row = (const float*)d_in[2];
    const float* w_col = (const float*)d_in[3];
    const float* b_col = (const float*)d_in[4];
    const float* g_a1  = (const float*)d_in[5];
    const float* be_a1 = (const float*)d_in[6];
    const float* g_a2  = (const float*)d_in[7];
    const float* be_a2 = (const float*)d_in[8];
    const float* w1    = (const float*)d_in[9];
    const float* b1f   = (const float*)d_in[10];
    const float* w2    = (const float*)d_in[11];
    const float* b2f_  = (const float*)d_in[12];
    const float* g_n1  = (const float*)d_in[13];
    const float* be_n1 = (const float*)d_in[14];
    const float* g_n2  = (const float*)d_in[15];
    const float* be_n2 = (const float*)d_in[16];
    float* outp = (float*)d_out;

    // ---- workspace layout (~160 MiB; strictly below working R5 footprint) ----
    char* wp = (char*)d_ws;
    auto alloc = [&](size_t bytes) -> void* {
        void* p = (void*)wp;
        wp += (bytes + 255) & ~(size_t)255;
        return p;
    };
    u16*   wPqk   = (u16*)alloc((size_t)1536 * 768 * 2);        // 2.25 MiB
    u16*   wPv    = (u16*)alloc((size_t)768 * 768 * 2);         // 1.13 MiB
    u16*   wPcol  = (u16*)alloc((size_t)2304 * 768 * 2);        // 3.38 MiB
    u16*   w1T    = (u16*)alloc((size_t)3072 * 768 * 2);        // 4.5 MiB
    u16*   w2T    = (u16*)alloc((size_t)768 * 3072 * 2);        // 4.5 MiB
    u16*   bufA   = (u16*)alloc((size_t)32768 * 768 * 2);       // 48 MiB: rowout/colout/ffb
    u16*   bufB   = (u16*)alloc((size_t)32768 * 768 * 2);       // 48 MiB: xb -> out1 -> ybf
    u16*   qkvg   = (u16*)alloc((size_t)8192 * 3072 * 2);       // 48 MiB: Q|K|V (36) / FFN hidden
    u16*   hidden = qkvg;
    u16*   xb     = bufB;    // bf16 x; dead before out1 is written
    u16*   ybf    = bufB;    // bf16 y; out1 dead when ln_ln runs
    float* y      = outp;    // f32 y in d_out until final in-place LN

    // ---- weight packing (f32 -> bf16) ----
    pack_qk_kernel<<<dim3(48, 24), 256, 0, stream>>>(w_row, wPqk);
    pack_v_kernel<<<dim3(24, 24), 256, 0, stream>>>(w_row, wPv);
    qkv_pack_kernel<<<dim3(72, 24), 256, 0, stream>>>(w_col, wPcol);
    transpose_kernel<<<dim3(96, 24), 256, 0, stream>>>(w1, w1T, 768, 3072);
    transpose_kernel<<<dim3(24, 96), 256, 0, stream>>>(w2, w2T, 3072, 768);
    cast_kernel<<<12288, 256, 0, stream>>>(x, xb);

    // ---- row (tied) attention, 4 groups of 16 heads ----
    for (int hg = 0; hg < 4; hg++) {
        // Q,K (N=384, s-major, dense head-major writes)
        gemm_dma<192, 8, 0, 1, 1><<<dim3(2, 256), 256, 0, stream>>>(
            xb, wPqk + (long)hg * 384 * 768, b_row, qkvg,
            384, 768, 0, 0, 0, hg * 192);
        // V (N=192, s-blocked, dense V^T writes)
        gemm_dma<192, 3, 0, 1, 0><<<dim3(1, 256), 256, 0, stream>>>(
            xb, wPv + (long)hg * 192 * 768, b_row, qkvg + 2 * REG,
            192, 768, 0, 0, 0, 1536 + hg * 192);
        // fused scores+softmax+PV
        flash_row_kernel<<<dim3(16, 16), 256, 0, stream>>>(
            qkvg, qkvg + REG, qkvg + 2 * REG, bufA, hg * 192);
    }
    // out1 = LN(x + rowout)   (xb dead from here; bufB becomes out1)
    ln_add_kernel<1, 0, 0><<<32768, 256, 0, stream>>>(x, bufA, g_a1, be_a1, bufB);

    // ---- col attention, 4 groups of 16 heads ----
    for (int hg = 0; hg < 4; hg++) {
        gemm_dma<192, 9, 0, 1, 1><<<dim3(3, 256), 256, 0, stream>>>(
            bufB, wPcol + (long)hg * 576 * 768, b_col, qkvg,
            576, 768, 0, 0, 0, hg * 192);
        col_attn_kernel<<<8192, 64, 0, stream>>>(
            qkvg, qkvg + REG, qkvg + 2 * REG, bufA, hg * 192);
    }
    // y = LN(x + LN(out1 + colout)) -> d_out (f32) + ybf (bf16, row-local alias)
    ln_ln_kernel<<<32768, 256, 0, stream>>>(
        bufB, bufA, x, g_a2, be_a2, g_n1, be_n1, y, ybf);

    // ---- FFN, 4 chunks of 8192 rows (hidden overlays qkvg) ----
    for (int mc = 0; mc < 4; mc++) {
        const long off = (long)mc * 8192 * 768;
        gemm_dma<192, 0, 1, 1, 0><<<dim3(16, 64), 256, 0, stream>>>(
            ybf + off, w1T, b1f, hidden, 3072, 768, 0, 0, 0, 0);
        gemm_dma<192, 0, 0, 1, 0><<<dim3(4, 64), 256, 0, stream>>>(
            hidden, w2T, b2f_, bufA + off, 768, 3072, 0, 0, 0, 0);
    }
    // final: out = LN(y + ffb), in-place over d_out (per-row, block-local)
    ln_add_kernel<1, 0, 1><<<32768, 256, 0, stream>>>(y, bufA, g_n2, be_n2, outp);
}